// Round 1
// baseline (532.822 us; speedup 1.0000x reference)
//
#include <hip/hip_runtime.h>

#define B_ 8
#define C_ 128
#define H_ 256
#define W_ 256
#define O_ 128
#define PAD 136   // 128 + 8 bf16: row stride 272 B = 68 dwords -> 4-bank rotation
#define WT 128    // pixels per workgroup

typedef __bf16 bf16x8 __attribute__((ext_vector_type(8)));
typedef float floatx4 __attribute__((ext_vector_type(4)));

__device__ __forceinline__ float ldpad(const float* __restrict__ xc, int y, int x) {
    // padded-frame coords y,x in [0, H+1]/[0, W+1]; zero outside [1, H]/[1, W]
    bool in = (y >= 1) & (y <= H_) & (x >= 1) & (x <= W_);
    return in ? xc[(y - 1) * W_ + (x - 1)] : 0.0f;
}

__global__ __launch_bounds__(256, 2)
void activeshift_kernel(const float* __restrict__ x,
                        const float* __restrict__ theta,
                        const float* __restrict__ wdw,
                        const float* __restrict__ wpw,
                        float* __restrict__ out)
{
    __shared__ __align__(16) __bf16 w_lds[O_ * PAD];  // [o][c] w_pw*w_dw, bf16
    __shared__ __align__(16) __bf16 s_lds[WT * PAD];  // [pixel][c] shifted x, bf16
    __shared__ int4 t_lds[C_];                        // {ft0, ft1, dy_bits, dx_bits}

    const int n  = blockIdx.x;
    const int wt = n & 1;
    const int h  = (n >> 1) & (H_ - 1);
    const int b  = n >> 9;
    const int w0 = wt * WT;
    const int tid = threadIdx.x;

    // ---- per-channel shift decomposition ----
    if (tid < C_) {
        float t0 = -theta[tid * 2 + 0];
        float t1 = -theta[tid * 2 + 1];
        float f0 = floorf(t0), f1 = floorf(t1);
        int4 v;
        v.x = (int)f0;
        v.y = (int)f1;
        v.z = __float_as_int(t0 - f0);
        v.w = __float_as_int(t1 - f1);
        t_lds[tid] = v;
    }

    // ---- stage w_eff = w_pw[o][c] * w_dw[c] as bf16, row-major [o][c] ----
    {
        const float dwv = wdw[tid & (C_ - 1)];
        #pragma unroll
        for (int i = 0; i < 64; ++i) {
            int idx = tid + i * 256;           // coalesced over lanes
            int c = idx & (C_ - 1);
            int o = idx >> 7;
            w_lds[o * PAD + c] = (__bf16)(wpw[idx] * dwv);
        }
    }
    __syncthreads();

    // ---- stage s: each thread = 1 pixel x 8 consecutive channels -> ds_write_b128 ----
    const int p    = tid & (WT - 1);   // pixel in strip
    const int half = tid >> 7;         // 0/1
    const int m  = h + 1;              // padded row coord
    const int nn = w0 + p + 1;         // padded col coord
    const float* xb = x + (size_t)b * C_ * H_ * W_;

    for (int it = 0; it < 8; ++it) {
        int c0 = it * 16 + half * 8;
        union { bf16x8 v; __bf16 e[8]; } pk;
        #pragma unroll
        for (int cc = 0; cc < 8; ++cc) {
            int c = c0 + cc;
            int4 tv = t_lds[c];                       // broadcast read
            float dy = __int_as_float(tv.z);
            float dx = __int_as_float(tv.w);
            int y0 = m + tv.x, y1 = y0 + 1;
            int x0 = nn + tv.y, x1 = x0 + 1;
            y0 = min(max(y0, 0), H_ + 1); y1 = min(max(y1, 0), H_ + 1);
            x0 = min(max(x0, 0), W_ + 1); x1 = min(max(x1, 0), W_ + 1);
            const float* xc = xb + (size_t)c * (H_ * W_);
            float v00 = ldpad(xc, y0, x0);
            float v01 = ldpad(xc, y0, x1);
            float v10 = ldpad(xc, y1, x0);
            float v11 = ldpad(xc, y1, x1);
            float r0 = v00 + dx * (v01 - v00);
            float r1 = v10 + dx * (v11 - v10);
            pk.e[cc] = (__bf16)(r0 + dy * (r1 - r0));
        }
        *(bf16x8*)&s_lds[p * PAD + c0] = pk.v;        // 16 B, conflict-free
    }
    __syncthreads();

    // ---- GEMM: out[o, pix] = sum_c w_eff[o,c] * s[c,pix]; 4 waves, 64x64 each ----
    const int wid  = tid >> 6;
    const int lane = tid & 63;
    const int wo   = (wid >> 1) * 64;   // o base of this wave
    const int wp   = (wid & 1) * 64;    // pixel base of this wave
    const int l15  = lane & 15;
    const int quad = lane >> 4;

    floatx4 acc[4][4];
    #pragma unroll
    for (int i = 0; i < 4; ++i)
        #pragma unroll
        for (int j = 0; j < 4; ++j)
            acc[i][j] = (floatx4){0.f, 0.f, 0.f, 0.f};

    #pragma unroll
    for (int k = 0; k < C_; k += 32) {
        bf16x8 af[4], bfr[4];
        #pragma unroll
        for (int i = 0; i < 4; ++i)  // A[m=o][k=c]: m=lane&15, k=quad*8+j
            af[i] = *(const bf16x8*)&w_lds[(wo + i * 16 + l15) * PAD + k + quad * 8];
        #pragma unroll
        for (int j = 0; j < 4; ++j)  // B[k=c][n=pix]: n=lane&15, k=quad*8+j
            bfr[j] = *(const bf16x8*)&s_lds[(wp + j * 16 + l15) * PAD + k + quad * 8];
        #pragma unroll
        for (int i = 0; i < 4; ++i)
            #pragma unroll
            for (int j = 0; j < 4; ++j)
                acc[i][j] = __builtin_amdgcn_mfma_f32_16x16x32_bf16(af[i], bfr[j], acc[i][j], 0, 0, 0);
    }

    // ---- store: D col = lane&15 = pixel, row = quad*4+reg = o ----
    const size_t HW = (size_t)H_ * W_;
    float* ob = out + (size_t)b * O_ * HW + (size_t)h * W_;
    #pragma unroll
    for (int i = 0; i < 4; ++i) {
        #pragma unroll
        for (int j = 0; j < 4; ++j) {
            int pcol  = w0 + wp + j * 16 + l15;
            int obase = wo + i * 16 + quad * 4;
            float* op = ob + (size_t)obase * HW + pcol;
            #pragma unroll
            for (int r = 0; r < 4; ++r)
                op[(size_t)r * HW] = acc[i][j][r];
        }
    }
}

extern "C" void kernel_launch(void* const* d_in, const int* in_sizes, int n_in,
                              void* d_out, int out_size, void* d_ws, size_t ws_size,
                              hipStream_t stream) {
    const float* x     = (const float*)d_in[0];
    const float* theta = (const float*)d_in[1];
    const float* wdw   = (const float*)d_in[2];
    const float* wpw   = (const float*)d_in[3];
    float* out = (float*)d_out;
    dim3 grid(B_ * H_ * (W_ / WT));   // 4096 workgroups
    activeshift_kernel<<<grid, dim3(256), 0, stream>>>(x, theta, wdw, wpw, out);
}